// Round 5
// baseline (104.890 us; speedup 1.0000x reference)
//
#include <hip/hip_runtime.h>

constexpr int B  = 16384;
constexpr int D  = 64;
constexpr int LA = 20;
constexpr int LC = 5;

// ds_swizzle xor pattern (BitMode): (xor_mask<<10) | 0x1F
template <int PAT>
__device__ __forceinline__ float swz(float v) {
    return __int_as_float(__builtin_amdgcn_ds_swizzle(__float_as_int(v), PAT));
}
// DPP row_ror:N add (row = 16 lanes)
template <int CTRL>
__device__ __forceinline__ float ror_add(float v) {
    const int r = __builtin_amdgcn_update_dpp(0, __float_as_int(v), CTRL, 0xF, 0xF, true);
    return v + __int_as_float(r);
}

// Reduce N independent values across a 32-lane half-wave, stage-interleaved.
// Stage 1: xor-16 via ds_swizzle (valid within 32-lane domain), then 4 DPP
// row-rotate stages. Every lane of the half ends with the full sum.
template <int N>
__device__ __forceinline__ void reduce32(float (&p)[N]) {
    #pragma unroll
    for (int l = 0; l < N; ++l) p[l] += swz<0x401F>(p[l]);   // xor 16
    #pragma unroll
    for (int l = 0; l < N; ++l) p[l] = ror_add<0x128>(p[l]); // ror 8
    #pragma unroll
    for (int l = 0; l < N; ++l) p[l] = ror_add<0x124>(p[l]); // ror 4
    #pragma unroll
    for (int l = 0; l < N; ++l) p[l] = ror_add<0x122>(p[l]); // ror 2
    #pragma unroll
    for (int l = 0; l < N; ++l) p[l] = ror_add<0x121>(p[l]); // ror 1
}

// 32 lanes per batch row, each lane holds 2 dims (float2). 8 rows per block.
// 2048 blocks -> 8 blocks/CU -> 32 waves/CU (full occupancy at <=64 VGPR).
__global__ __launch_bounds__(256, 8) void aspect_kernel(
    const int*   __restrict__ user_id,
    const int*   __restrict__ artists_id,
    const int*   __restrict__ categories_id,
    const float* __restrict__ user_factors,
    const float* __restrict__ entity_factors,
    const float* __restrict__ relation_k,
    float*       __restrict__ out)
{
    const int tid = threadIdx.x;
    const int sl  = tid & 31;                 // sub-lane within 32-lane row group
    const int grp = tid >> 5;                 // row group within block (0..7)
    const int b   = (blockIdx.x << 3) + grp;  // 2048 blocks * 8 rows == B

    // Output layout: prediction(B) | scores(B*3) | c_act(B) | c_dir(B) | niubi_act(B*LA) | niubi_dir(B*LC)
    float* pred    = out;
    float* scores  = out + B;
    float* c_act_o = out + (size_t)4 * B;
    float* c_dir_o = out + (size_t)5 * B;
    float* niubiA  = out + (size_t)6 * B;
    float* niubiC  = niubiA + (size_t)B * LA;

    const int    uid = user_id[b];
    const float2 u2  = *(const float2*)&user_factors[(size_t)uid * D + sl * 2];

    // ---- artists: 20 gathered dot products (indices via 5x int4) ----
    const int4* aidv = (const int4*)&artists_id[(size_t)b * LA];  // 80B offset: 16B-aligned
    float pa[LA];
    #pragma unroll
    for (int k = 0; k < 5; ++k) {
        const int4 aw = aidv[k];
        const int idx[4] = {aw.x, aw.y, aw.z, aw.w};
        #pragma unroll
        for (int j = 0; j < 4; ++j) {
            const float2 e = *(const float2*)&entity_factors[(size_t)idx[j] * D + sl * 2];
            pa[k * 4 + j] = fmaf(e.x, u2.x, e.y * u2.y);
        }
    }
    reduce32(pa);
    float sumA = 0.f;
    #pragma unroll
    for (int l = 0; l < LA; ++l) sumA += pa[l];
    // store niubi_act now to shorten pa's live range
    if (sl < 5) {
        float4 v;
        v.x = sl == 0 ? pa[0] : sl == 1 ? pa[4]  : sl == 2 ? pa[8]  : sl == 3 ? pa[12] : pa[16];
        v.y = sl == 0 ? pa[1] : sl == 1 ? pa[5]  : sl == 2 ? pa[9]  : sl == 3 ? pa[13] : pa[17];
        v.z = sl == 0 ? pa[2] : sl == 1 ? pa[6]  : sl == 2 ? pa[10] : sl == 3 ? pa[14] : pa[18];
        v.w = sl == 0 ? pa[3] : sl == 1 ? pa[7]  : sl == 2 ? pa[11] : sl == 3 ? pa[15] : pa[19];
        *(float4*)&niubiA[(size_t)b * LA + sl * 4] = v;
    }
    const float c_act = sumA * (1.f / LA);

    // ---- categories: 5 gathered dot products ----
    float pc[LC];
    #pragma unroll
    for (int l = 0; l < LC; ++l) {
        const int    idx = categories_id[b * LC + l];
        const float2 e   = *(const float2*)&entity_factors[(size_t)idx * D + sl * 2];
        pc[l] = fmaf(e.x, u2.x, e.y * u2.y);
    }
    reduce32(pc);
    float sumC = 0.f;
    #pragma unroll
    for (int l = 0; l < LC; ++l) sumC += pc[l];
    if (sl < LC) {
        const float v = sl == 0 ? pc[0] : sl == 1 ? pc[1] : sl == 2 ? pc[2] : sl == 3 ? pc[3] : pc[4];
        niubiC[(size_t)b * LC + sl] = v;
    }
    const float c_dir = sumC * (1.f / LC);

    // ---- users @ relation_k (D x 3), leaky_relu, softmax over 3 ----
    float ps[3];
    {
        const int d0 = sl * 2;
        ps[0] = fmaf(u2.x, relation_k[(d0+0)*3+0], u2.y * relation_k[(d0+1)*3+0]);
        ps[1] = fmaf(u2.x, relation_k[(d0+0)*3+1], u2.y * relation_k[(d0+1)*3+1]);
        ps[2] = fmaf(u2.x, relation_k[(d0+0)*3+2], u2.y * relation_k[(d0+1)*3+2]);
    }
    reduce32(ps);
    float q0 = ps[0] >= 0.f ? ps[0] : 0.2f * ps[0];
    float q1 = ps[1] >= 0.f ? ps[1] : 0.2f * ps[1];
    float q2 = ps[2] >= 0.f ? ps[2] : 0.2f * ps[2];
    const float m   = fmaxf(q0, fmaxf(q1, q2));
    const float e0  = __expf(q0 - m), e1 = __expf(q1 - m), e2 = __expf(q2 - m);
    const float inv = 1.f / (e0 + e1 + e2);
    const float s0 = e0 * inv, s1 = e1 * inv, s2 = e2 * inv;

    if (sl < 3) {
        const float v = sl == 0 ? s0 : sl == 1 ? s1 : s2;
        scores[b * 3 + sl] = v;
    }
    if (sl == 0) {
        pred[b]    = (c_act * s0 + c_dir * s1) / (s0 + s1);
        c_act_o[b] = c_act;
        c_dir_o[b] = c_dir;
    }
}

extern "C" void kernel_launch(void* const* d_in, const int* in_sizes, int n_in,
                              void* d_out, int out_size, void* d_ws, size_t ws_size,
                              hipStream_t stream) {
    const int*   user_id        = (const int*)d_in[0];
    const int*   artists_id     = (const int*)d_in[1];
    const int*   categories_id  = (const int*)d_in[2];
    // d_in[3] = rate (unused scalar)
    const float* user_factors   = (const float*)d_in[4];
    const float* entity_factors = (const float*)d_in[5];
    const float* relation_k     = (const float*)d_in[6];
    float*       out            = (float*)d_out;

    const int rows_per_block = 8;                // 8 groups of 32 lanes = 256 threads
    const int grid = B / rows_per_block;         // 2048
    aspect_kernel<<<grid, 256, 0, stream>>>(
        user_id, artists_id, categories_id, user_factors, entity_factors, relation_k, out);
}